// Round 7
// baseline (289.050 us; speedup 1.0000x reference)
//
#include <hip/hip_runtime.h>
#include <math.h>

#define KN   20000
#define IN_  50000
#define DD   128
#define NN   70000
#define E1N  320000
#define E2N  640000

// gemm3: 64 rows/block
#define GB0  313     // ceil(20000/64)
#define GB1  1094    // ceil(70000/64)
#define GB2  1094

typedef _Float16 f16x8 __attribute__((ext_vector_type(8)));
typedef float floatx4 __attribute__((ext_vector_type(4)));
typedef float floatx2 __attribute__((ext_vector_type(2)));

__device__ __forceinline__ unsigned f2bf(float x) {
  unsigned u = __float_as_uint(x);
  return (u + 0x7FFFu + ((u >> 16) & 1u)) >> 16;   // RNE
}
__device__ __forceinline__ unsigned packbf(float a, float b) {
  return f2bf(a) | (f2bf(b) << 16);
}
__device__ __forceinline__ float bf_lo(unsigned u) { return __uint_as_float(u << 16); }
__device__ __forceinline__ float bf_hi(unsigned u) { return __uint_as_float(u & 0xFFFF0000u); }
__device__ __forceinline__ floatx2 bfp(unsigned u) {
  floatx2 r; r.x = bf_lo(u); r.y = bf_hi(u); return r;
}

// Fused: (a) convert 4 weight matrices to MFMA-fragment-ordered fp16,
// (b) count edges per dst segment, recording each edge's rank.
__global__ __launch_bounds__(256) void prep(
    const float* __restrict__ W0, const float* __restrict__ W1,
    const float* __restrict__ W2, const float* __restrict__ W3,
    short* __restrict__ wfr,
    const int* __restrict__ ddst, const int* __restrict__ kedst, const int* __restrict__ ekdst,
    int* __restrict__ cnt_dir, int* __restrict__ cnt_ke, int* __restrict__ cnt_ek,
    unsigned short* __restrict__ rank_dir, unsigned short* __restrict__ rank_ke,
    unsigned short* __restrict__ rank_ek)
{
  int b = blockIdx.x;
  if (b < 32) {
    int wsel = b >> 3;
    const float* W = (wsel == 0) ? W0 : (wsel == 1) ? W1 : (wsel == 2) ? W2 : W3;
    int fi = (b & 7) * 256 + threadIdx.x;    // 0..2047
    int l = fi & 63, chunk = (fi >> 6) & 3, t = fi >> 8;
    int col = t * 16 + (l & 15);
    int kbase = chunk * 32 + (l >> 4) * 8;
    f16x8 hv;
#pragma unroll
    for (int j = 0; j < 8; ++j) hv[j] = (_Float16)W[(kbase + j) * 128 + col];
    ((f16x8*)(wfr + wsel * 16384))[fi] = hv;
    return;
  }
  int i = (b - 32) * 256 + threadIdx.x;
  if (i < E1N) {
    rank_dir[i] = (unsigned short)atomicAdd(&cnt_dir[ddst[i]], 1);
  } else if (i < E1N + E2N) {
    int e = i - E1N;
    int d = kedst[e];
    if (d >= IN_) rank_ke[e] = (unsigned short)atomicAdd(&cnt_ke[d - IN_], 1);
  } else {
    int e = i - E1N - E2N;
    int d = ekdst[e];
    if (d < IN_) rank_ek[e] = (unsigned short)atomicAdd(&cnt_ek[d], 1);
  }
}

// 3x MFMA gemms, fp16 2-term. 64 rows/block, 32 KB LDS.
__global__ __launch_bounds__(256, 4) void gemm3(
    const float* __restrict__ kn, const float* __restrict__ ex,
    const short* __restrict__ wfr,
    const float* __restrict__ a_dir, const float* __restrict__ a_ke, const float* __restrict__ a_ek,
    unsigned* __restrict__ zb_dir, unsigned* __restrict__ zb_ke, unsigned* __restrict__ zb_ek,
    float* __restrict__ sds, float* __restrict__ sdd,
    float* __restrict__ sks, float* __restrict__ skd,
    float* __restrict__ ses, float* __restrict__ sed)
{
  __shared__ short sW[16384];   // 32 KB fp16 fragments
  const int bid = blockIdx.x;
  const int tid = threadIdx.x;

  const float *h1, *h2, *avec;
  unsigned* zb;
  float *ssrc, *sdst;
  const short* wf;
  int split, rows, tile;
  if (bid < GB0) {
    tile = bid; rows = KN; split = KN; h1 = kn; h2 = kn;
    wf = wfr; avec = a_dir; zb = zb_dir; ssrc = sds; sdst = sdd;
  } else if (bid < GB0 + GB1) {
    tile = bid - GB0; rows = NN; split = IN_; h1 = ex; h2 = kn;
    wf = wfr + 16384; avec = a_ke; zb = zb_ke; ssrc = sks; sdst = skd;
  } else {
    tile = bid - GB0 - GB1; rows = NN; split = IN_; h1 = ex; h2 = kn;
    wf = wfr + 32768; avec = a_ek; zb = zb_ek; ssrc = ses; sdst = sed;
  }

  {
    const int4* gs = (const int4*)wf;
    int4* ls = (int4*)sW;
#pragma unroll
    for (int it = 0; it < 8; ++it) ls[it * 256 + tid] = gs[it * 256 + tid];
  }
  __syncthreads();

  const int lane = tid & 63;
  const int wv = tid >> 6;
  const int q = lane >> 4;
  const int m = lane & 15;
  const int r = tile * 64 + wv * 16 + m;
  const int rc = (r < rows) ? r : (rows - 1);
  const float* hp = (rc < split) ? (h1 + (size_t)rc * 128)
                                 : (h2 + (size_t)(rc - split) * 128);

  floatx4 acc[8];
#pragma unroll
  for (int t = 0; t < 8; ++t) { acc[t][0]=0.f; acc[t][1]=0.f; acc[t][2]=0.f; acc[t][3]=0.f; }

#pragma unroll
  for (int chunk = 0; chunk < 4; ++chunk) {
    float4 v0 = *(const float4*)(hp + chunk * 32 + q * 8);
    float4 v1 = *(const float4*)(hp + chunk * 32 + q * 8 + 4);
    float vs[8] = {v0.x, v0.y, v0.z, v0.w, v1.x, v1.y, v1.z, v1.w};
    f16x8 ahi, alo;
#pragma unroll
    for (int j = 0; j < 8; ++j) {
      _Float16 h = (_Float16)vs[j];
      ahi[j] = h;
      alo[j] = (_Float16)(vs[j] - (float)h);
    }
#pragma unroll
    for (int t = 0; t < 8; ++t) {
      f16x8 bh = ((const f16x8*)sW)[(t * 4 + chunk) * 64 + lane];
      acc[t] = __builtin_amdgcn_mfma_f32_16x16x32_f16(bh, ahi, acc[t], 0, 0, 0);
      acc[t] = __builtin_amdgcn_mfma_f32_16x16x32_f16(bh, alo, acc[t], 0, 0, 0);
    }
  }

  if (r < rows) {
    unsigned* zrow = zb + (size_t)r * 64;
#pragma unroll
    for (int t = 0; t < 8; ++t) {
      uint2 pk;
      pk.x = packbf(acc[t][0], acc[t][1]);
      pk.y = packbf(acc[t][2], acc[t][3]);
      *(uint2*)(zrow + t * 8 + q * 2) = pk;
    }
  }
  float d1 = 0.f, d2 = 0.f;
#pragma unroll
  for (int t = 0; t < 8; ++t) {
    float4 wa = *(const float4*)(avec + t * 16 + q * 4);
    float4 wb = *(const float4*)(avec + 128 + t * 16 + q * 4);
    d1 += acc[t][0] * wa.x + acc[t][1] * wa.y + acc[t][2] * wa.z + acc[t][3] * wa.w;
    d2 += acc[t][0] * wb.x + acc[t][1] * wb.y + acc[t][2] * wb.z + acc[t][3] * wb.w;
  }
  d1 += __shfl_xor(d1, 16, 64); d1 += __shfl_xor(d1, 32, 64);
  d2 += __shfl_xor(d2, 16, 64); d2 += __shfl_xor(d2, 32, 64);
  if (q == 0 && r < rows) { ssrc[r] = d1; sdst[r] = d2; }
}

// CSR allocation: wave shuffle-scan + 1 atomic/wave.
__global__ __launch_bounds__(256) void alloc_off(
    const int* __restrict__ cnt_dir, int* __restrict__ st_dir,
    const int* __restrict__ cnt_ke,  int* __restrict__ st_ke,
    const int* __restrict__ cnt_ek,  int* __restrict__ st_ek,
    int* __restrict__ totals)
{
  int b = blockIdx.x;
  const int* cnt; int* st; int* tot; int n, i0;
  if (b < 79)       { cnt = cnt_dir; st = st_dir; tot = totals + 0; n = KN;  i0 = b * 256; }
  else if (b < 158) { cnt = cnt_ke;  st = st_ke;  tot = totals + 1; n = KN;  i0 = (b - 79) * 256; }
  else              { cnt = cnt_ek;  st = st_ek;  tot = totals + 2; n = IN_; i0 = (b - 158) * 256; }
  int i = i0 + threadIdx.x;
  int lane = threadIdx.x & 63;
  int v = (i < n) ? cnt[i] : 0;
  int x = v;
#pragma unroll
  for (int o = 1; o < 64; o <<= 1) {
    int t = __shfl_up(x, o, 64);
    if (lane >= o) x += t;
  }
  int base = 0;
  if (lane == 63) base = atomicAdd(tot, x);
  base = __shfl(base, 63, 64);
  if (i < n) st[i] = base + x - v;
}

// atomic-free placement; also precomputes the edge softmax weight
// w = exp(leaky(sS[src] + sD[dst])) so gather does pure weighted gather.
__global__ __launch_bounds__(256) void fill_edges(
    const int* __restrict__ dsrc, const int* __restrict__ ddst,
    const int* __restrict__ kesrc, const int* __restrict__ kedst,
    const int* __restrict__ eksrc, const int* __restrict__ ekdst,
    const unsigned short* __restrict__ rank_dir, const unsigned short* __restrict__ rank_ke,
    const unsigned short* __restrict__ rank_ek,
    const float* __restrict__ sds, const float* __restrict__ sdd,
    const float* __restrict__ sks, const float* __restrict__ skd,
    const float* __restrict__ ses, const float* __restrict__ sed,
    const int* __restrict__ st_dir, int2* __restrict__ ep_dir,
    const int* __restrict__ st_ke,  int2* __restrict__ ep_ke,
    const int* __restrict__ st_ek,  int2* __restrict__ ep_ek)
{
  int i = blockIdx.x * 256 + threadIdx.x;
  if (i < E1N) {
    int d = ddst[i];
    int s = dsrc[i];
    float x = sds[s] + sdd[d];
    x = (x > 0.f) ? x : 0.01f * x;
    ep_dir[st_dir[d] + rank_dir[i]] = make_int2(s, __float_as_int(__expf(x)));
  } else if (i < E1N + E2N) {
    int e = i - E1N;
    int d = kedst[e];
    if (d >= IN_) {
      int s = kesrc[e];
      float x = sks[s] + skd[d];
      x = (x > 0.f) ? x : 0.01f * x;
      ep_ke[st_ke[d - IN_] + rank_ke[e]] = make_int2(s, __float_as_int(__expf(x)));
    }
  } else {
    int e = i - E1N - E2N;
    int d = ekdst[e];
    if (d < IN_) {
      int s = eksrc[e];
      float x = ses[s] + sed[d];
      x = (x > 0.f) ? x : 0.01f * x;
      ep_ek[st_ek[d] + rank_ek[e]] = make_int2(s, __float_as_int(__expf(x)));
    }
  }
}

// One 16-lane group per dst segment (wave = 4 independent segments).
// 4-deep unrolled weighted gather of bf16 rows; no cross-group reduction.
__global__ __launch_bounds__(256) void gat_gather(
    const int* __restrict__ st_dir, const int* __restrict__ cnt_dir, const int2* __restrict__ ep_dir,
    const unsigned* __restrict__ zb_dir, float* __restrict__ A,
    const int* __restrict__ st_ke, const int* __restrict__ cnt_ke, const int2* __restrict__ ep_ke,
    const unsigned* __restrict__ zb_ke, float* __restrict__ Bm,
    const int* __restrict__ st_ek, const int* __restrict__ cnt_ek, const int2* __restrict__ ep_ek,
    const unsigned* __restrict__ zb_ek, float* __restrict__ Cout)
{
  int g = (blockIdx.x * 256 + threadIdx.x) >> 4;   // global group = segment
  int gl = threadIdx.x & 15;
  const int *st, *cn; const int2* ep;
  const unsigned* zb;
  float* out;
  int seg;
  if (g < KN)                { seg = g;          st = st_dir; cn = cnt_dir; ep = ep_dir; zb = zb_dir; out = A; }
  else if (g < 2 * KN)       { seg = g - KN;     st = st_ke;  cn = cnt_ke;  ep = ep_ke;  zb = zb_ke;  out = Bm; }
  else if (g < 2 * KN + IN_) { seg = g - 2 * KN; st = st_ek;  cn = cnt_ek;  ep = ep_ek;  zb = zb_ek;  out = Cout; }
  else return;

  int b = st[seg], n = cn[seg], e = b + n;
  floatx2 av0, av1, av2, av3;
  av0 = 0.f; av1 = 0.f; av2 = 0.f; av3 = 0.f;
  float den = 0.f;

  int i = b;
  for (; i + 3 < e; i += 4) {
    int4 pa = *(const int4*)(ep + i);       // edges i, i+1
    int4 pb = *(const int4*)(ep + i + 2);   // edges i+2, i+3
    uint4 z0 = *(const uint4*)(zb + (size_t)pa.x * 64 + gl * 4);
    uint4 z1 = *(const uint4*)(zb + (size_t)pa.z * 64 + gl * 4);
    uint4 z2 = *(const uint4*)(zb + (size_t)pb.x * 64 + gl * 4);
    uint4 z3 = *(const uint4*)(zb + (size_t)pb.z * 64 + gl * 4);
    float w0 = __int_as_float(pa.y), w1 = __int_as_float(pa.w);
    float w2 = __int_as_float(pb.y), w3 = __int_as_float(pb.w);
    den += (w0 + w1) + (w2 + w3);
    av0 += bfp(z0.x) * w0; av1 += bfp(z0.y) * w0; av2 += bfp(z0.z) * w0; av3 += bfp(z0.w) * w0;
    av0 += bfp(z1.x) * w1; av1 += bfp(z1.y) * w1; av2 += bfp(z1.z) * w1; av3 += bfp(z1.w) * w1;
    av0 += bfp(z2.x) * w2; av1 += bfp(z2.y) * w2; av2 += bfp(z2.z) * w2; av3 += bfp(z2.w) * w2;
    av0 += bfp(z3.x) * w3; av1 += bfp(z3.y) * w3; av2 += bfp(z3.z) * w3; av3 += bfp(z3.w) * w3;
  }
  for (; i < e; ++i) {
    int2 pe = ep[i];
    uint4 z = *(const uint4*)(zb + (size_t)pe.x * 64 + gl * 4);
    float w = __int_as_float(pe.y);
    den += w;
    av0 += bfp(z.x) * w; av1 += bfp(z.y) * w; av2 += bfp(z.z) * w; av3 += bfp(z.w) * w;
  }

  float inv = (n > 0) ? 1.f / den : 0.f;
  av0 *= inv; av1 *= inv; av2 *= inv; av3 *= inv;

  float* op = out + (size_t)seg * 128 + gl * 8;
  *(float4*)op       = make_float4(av0.x, av0.y, av1.x, av1.y);
  *(float4*)(op + 4) = make_float4(av2.x, av2.y, av3.x, av3.y);
}

// rel-gemm on Am and Bm rows (fp16 2-term) + tanh/w2 scores + softmax +
// combine from REGISTERS (no re-read of Am/Bm).
__global__ __launch_bounds__(256, 2) void relgemm_combine(
    const float* __restrict__ Am, const float* __restrict__ Bm,
    const short* __restrict__ wfr_rel,
    const float* __restrict__ rb1, const float* __restrict__ rw2,
    float* __restrict__ out)
{
  __shared__ short sW[16384];
  const int tid = threadIdx.x;
  {
    const int4* gs = (const int4*)wfr_rel;
    int4* ls = (int4*)sW;
#pragma unroll
    for (int it = 0; it < 8; ++it) ls[it * 256 + tid] = gs[it * 256 + tid];
  }
  __syncthreads();

  const int lane = tid & 63;
  const int wv = tid >> 6;
  const int q = lane >> 4;
  const int m = lane & 15;
  const int r = blockIdx.x * 64 + wv * 16 + m;
  const int rc = (r < KN) ? r : (KN - 1);
  const float* hA = Am + (size_t)rc * 128;
  const float* hB = Bm + (size_t)rc * 128;

  floatx4 accA[8], accB[8];
#pragma unroll
  for (int t = 0; t < 8; ++t) {
    accA[t][0]=0.f; accA[t][1]=0.f; accA[t][2]=0.f; accA[t][3]=0.f;
    accB[t][0]=0.f; accB[t][1]=0.f; accB[t][2]=0.f; accB[t][3]=0.f;
  }

  float asv[4][8], bsv[4][8];   // lane's held row values (reused for combine)

#pragma unroll
  for (int chunk = 0; chunk < 4; ++chunk) {
    float4 a0 = *(const float4*)(hA + chunk * 32 + q * 8);
    float4 a1 = *(const float4*)(hA + chunk * 32 + q * 8 + 4);
    float4 b0 = *(const float4*)(hB + chunk * 32 + q * 8);
    float4 b1 = *(const float4*)(hB + chunk * 32 + q * 8 + 4);
    asv[chunk][0]=a0.x; asv[chunk][1]=a0.y; asv[chunk][2]=a0.z; asv[chunk][3]=a0.w;
    asv[chunk][4]=a1.x; asv[chunk][5]=a1.y; asv[chunk][6]=a1.z; asv[chunk][7]=a1.w;
    bsv[chunk][0]=b0.x; bsv[chunk][1]=b0.y; bsv[chunk][2]=b0.z; bsv[chunk][3]=b0.w;
    bsv[chunk][4]=b1.x; bsv[chunk][5]=b1.y; bsv[chunk][6]=b1.z; bsv[chunk][7]=b1.w;
    f16x8 ahiA, aloA, ahiB, aloB;
#pragma unroll
    for (int j = 0; j < 8; ++j) {
      float a = asv[chunk][j], bvl = bsv[chunk][j];
      _Float16 ha = (_Float16)a;
      ahiA[j] = ha; aloA[j] = (_Float16)(a - (float)ha);
      _Float16 hb = (_Float16)bvl;
      ahiB[j] = hb; aloB[j] = (_Float16)(bvl - (float)hb);
    }
#pragma unroll
    for (int t = 0; t < 8; ++t) {
      f16x8 bh = ((const f16x8*)sW)[(t * 4 + chunk) * 64 + lane];
      accA[t] = __builtin_amdgcn_mfma_f32_16x16x32_f16(bh, ahiA, accA[t], 0, 0, 0);
      accA[t] = __builtin_amdgcn_mfma_f32_16x16x32_f16(bh, aloA, accA[t], 0, 0, 0);
      accB[t] = __builtin_amdgcn_mfma_f32_16x16x32_f16(bh, ahiB, accB[t], 0, 0, 0);
      accB[t] = __builtin_amdgcn_mfma_f32_16x16x32_f16(bh, aloB, accB[t], 0, 0, 0);
    }
  }

  float p1 = 0.f, p2 = 0.f;
#pragma unroll
  for (int t = 0; t < 8; ++t) {
    float4 bb = *(const float4*)(rb1 + t * 16 + q * 4);
    float4 ww = *(const float4*)(rw2 + t * 16 + q * 4);
    p1 += tanhf(accA[t][0] + bb.x) * ww.x + tanhf(accA[t][1] + bb.y) * ww.y +
          tanhf(accA[t][2] + bb.z) * ww.z + tanhf(accA[t][3] + bb.w) * ww.w;
    p2 += tanhf(accB[t][0] + bb.x) * ww.x + tanhf(accB[t][1] + bb.y) * ww.y +
          tanhf(accB[t][2] + bb.z) * ww.z + tanhf(accB[t][3] + bb.w) * ww.w;
  }
  p1 += __shfl_xor(p1, 16, 64); p1 += __shfl_xor(p1, 32, 64);
  p2 += __shfl_xor(p2, 16, 64); p2 += __shfl_xor(p2, 32, 64);

  float mx = fmaxf(p1, p2);
  float e1 = __expf(p1 - mx), e2 = __expf(p2 - mx);
  float al = e1 / (e1 + e2), be = e2 / (e1 + e2);

  if (r < KN) {
#pragma unroll
    for (int chunk = 0; chunk < 4; ++chunk) {
      float o[8];
#pragma unroll
      for (int j = 0; j < 8; ++j) o[j] = al * asv[chunk][j] + be * bsv[chunk][j];
      float* op = out + (size_t)r * 128 + chunk * 32 + q * 8;
      *(float4*)op       = make_float4(o[0], o[1], o[2], o[3]);
      *(float4*)(op + 4) = make_float4(o[4], o[5], o[6], o[7]);
    }
  }
}

extern "C" void kernel_launch(void* const* d_in, const int* in_sizes, int n_in,
                              void* d_out, int out_size, void* d_ws, size_t ws_size,
                              hipStream_t stream) {
  const float* kn    = (const float*)d_in[0];
  const float* ex    = (const float*)d_in[1];
  const float* W_dir = (const float*)d_in[2];
  const float* a_dir = (const float*)d_in[3];
  const float* W_ke  = (const float*)d_in[4];
  const float* a_ke  = (const float*)d_in[5];
  const float* W_ek  = (const float*)d_in[6];
  const float* a_ek  = (const float*)d_in[7];
  const float* rW1   = (const float*)d_in[8];
  const float* rb1   = (const float*)d_in[9];
  const float* rw2   = (const float*)d_in[10];
  const int* dsrc    = (const int*)d_in[11];
  const int* ddst    = (const int*)d_in[12];
  const int* kesrc   = (const int*)d_in[13];
  const int* kedst   = (const int*)d_in[14];
  const int* eksrc   = (const int*)d_in[15];
  const int* ekdst   = (const int*)d_in[16];
  float* out = (float*)d_out;

  char* p = (char*)d_ws;
  auto alloc = [&](size_t bytes) {
    char* r = p;
    p += (bytes + 255) & ~(size_t)255;
    return r;
  };
  unsigned* zb_dir = (unsigned*)alloc((size_t)KN * 64 * 4);
  unsigned* zb_ke  = (unsigned*)alloc((size_t)NN * 64 * 4);
  unsigned* zb_ek  = (unsigned*)alloc((size_t)NN * 64 * 4);
  float* Am    = (float*)alloc((size_t)KN * 128 * 4);
  float* Bmat  = (float*)alloc((size_t)KN * 128 * 4);
  short* wfr   = (short*)alloc((size_t)4 * 16384 * 2);
  float* sds = (float*)alloc(KN * 4);
  float* sdd = (float*)alloc(KN * 4);
  float* sks = (float*)alloc(NN * 4);
  float* skd = (float*)alloc(NN * 4);
  float* ses = (float*)alloc(NN * 4);
  float* sed = (float*)alloc(NN * 4);
  int* cntblk  = (int*)alloc((size_t)(2 * KN + IN_ + 64) * 4);
  int* cnt_dir = cntblk;
  int* cnt_ke  = cntblk + KN;
  int* cnt_ek  = cntblk + 2 * KN;
  int* totals  = cntblk + 2 * KN + IN_;
  int* st_dir = (int*)alloc(KN * 4);
  int* st_ke  = (int*)alloc(KN * 4);
  int* st_ek  = (int*)alloc(IN_ * 4);
  unsigned short* rank_dir = (unsigned short*)alloc((size_t)E1N * 2);
  unsigned short* rank_ke  = (unsigned short*)alloc((size_t)E2N * 2);
  unsigned short* rank_ek  = (unsigned short*)alloc((size_t)E2N * 2);
  int2* ep_dir = (int2*)alloc((size_t)E1N * 8);
  int2* ep_ke  = (int2*)alloc((size_t)E2N * 8);
  int2* ep_ek  = (int2*)alloc((size_t)E2N * 8);

  hipMemsetAsync(cntblk, 0, (size_t)(2 * KN + IN_ + 64) * 4, stream);

  prep<<<32 + (E1N + 2 * E2N) / 256, 256, 0, stream>>>(
      W_dir, W_ke, W_ek, rW1, wfr,
      ddst, kedst, ekdst, cnt_dir, cnt_ke, cnt_ek,
      rank_dir, rank_ke, rank_ek);

  gemm3<<<GB0 + GB1 + GB2, 256, 0, stream>>>(
      kn, ex, wfr, a_dir, a_ke, a_ek,
      zb_dir, zb_ke, zb_ek,
      sds, sdd, sks, skd, ses, sed);

  alloc_off<<<354, 256, 0, stream>>>(cnt_dir, st_dir, cnt_ke, st_ke, cnt_ek, st_ek, totals);

  fill_edges<<<(E1N + 2 * E2N) / 256, 256, 0, stream>>>(
      dsrc, ddst, kesrc, kedst, eksrc, ekdst,
      rank_dir, rank_ke, rank_ek,
      sds, sdd, sks, skd, ses, sed,
      st_dir, ep_dir, st_ke, ep_ke, st_ek, ep_ek);

  gat_gather<<<(2 * KN + IN_) / 16, 256, 0, stream>>>(
      st_dir, cnt_dir, ep_dir, zb_dir, Am,
      st_ke,  cnt_ke,  ep_ke,  zb_ke,  Bmat,
      st_ek,  cnt_ek,  ep_ek,  zb_ek,  out + (size_t)KN * 128);

  relgemm_combine<<<313, 256, 0, stream>>>(Am, Bmat, wfr + 3 * 16384, rb1, rw2, out);
}